// Round 5
// baseline (178.515 us; speedup 1.0000x reference)
//
#include <hip/hip_runtime.h>

typedef unsigned short u16;
typedef unsigned int u32;
typedef short bf16x8 __attribute__((ext_vector_type(8)));
typedef float f32x4 __attribute__((ext_vector_type(4)));

#define HH 128

__device__ __forceinline__ u16 f2bf(float f) {
  u32 u = __float_as_uint(f);
  u += 0x7fffu + ((u >> 16) & 1u);  // round-to-nearest-even
  return (u16)(u >> 16);
}
__device__ __forceinline__ u32 pack2(float a, float b) {
  return (u32)f2bf(a) | ((u32)f2bf(b) << 16);
}
__device__ __forceinline__ float bf2f(u16 h) {
  return __uint_as_float(((u32)h) << 16);
}

// ---------------------------------------------------------------------------
// Pre-pass: fused W_comb (bf16), chunk-transposed + bank-swizzled, into d_ws.
// Chunk index (((q*16+kc)*512+n)*4+p) holds W[k = kc*32 + lq*8 + j][col n],
// lq = p ^ (n&3) ^ ((n>>2)&3).
// Fused: k<384 -> W_cat[k][q*512+n]; k>=384 -> (n<128 ? 0 : W_exp[k-384][q*384+n-128])
// ---------------------------------------------------------------------------
__global__ __launch_bounds__(256) void prep_w(const float* __restrict__ Wcat,
                                              const float* __restrict__ Wexp,
                                              u16* __restrict__ Wc) {
  const int bx = blockIdx.x;      // 512 blocks: ((q*16+kc)*8 + nt)
  const int nt = bx & 7;
  const int kc = (bx >> 3) & 15;
  const int q = bx >> 7;
  __shared__ u16 T[32 * 72];      // [k-in-chunk][64 cols], stride 72 (pad)

  const int tid = threadIdx.x;
  const int r = tid >> 3;
  const int c8 = (tid & 7) * 8;
  float v[8];
  if (kc < 12) {
    const float* src =
        Wcat + (size_t)(kc * 32 + r) * 2048 + q * 512 + nt * 64 + c8;
    float4 a = *(const float4*)src;
    float4 b = *(const float4*)(src + 4);
    v[0] = a.x; v[1] = a.y; v[2] = a.z; v[3] = a.w;
    v[4] = b.x; v[5] = b.y; v[6] = b.z; v[7] = b.w;
  } else if (nt >= 2) {
    const float* src = Wexp + (size_t)((kc - 12) * 32 + r) * 1536 + q * 384 +
                       nt * 64 + c8 - 128;
    float4 a = *(const float4*)src;
    float4 b = *(const float4*)(src + 4);
    v[0] = a.x; v[1] = a.y; v[2] = a.z; v[3] = a.w;
    v[4] = b.x; v[5] = b.y; v[6] = b.z; v[7] = b.w;
  } else {
#pragma unroll
    for (int j = 0; j < 8; ++j) v[j] = 0.f;
  }
  uint4 pk;
  pk.x = pack2(v[0], v[1]);
  pk.y = pack2(v[2], v[3]);
  pk.z = pack2(v[4], v[5]);
  pk.w = pack2(v[6], v[7]);
  *(uint4*)&T[r * 72 + c8] = pk;
  __syncthreads();

  const int p = tid & 3;
  const int nl = tid >> 2;  // 0..63 local col
  const int lq = p ^ (nl & 3) ^ ((nl >> 2) & 3);
  u16 w[8];
#pragma unroll
  for (int j = 0; j < 8; ++j) w[j] = T[(lq * 8 + j) * 72 + nl];
  uint4 o;
  o.x = (u32)w[0] | ((u32)w[1] << 16);
  o.y = (u32)w[2] | ((u32)w[3] << 16);
  o.z = (u32)w[4] | ((u32)w[5] << 16);
  o.w = (u32)w[6] | ((u32)w[7] << 16);
  const size_t idx = ((size_t)((q * 16 + kc) * 512) + nt * 64 + nl) * 4 + p;
  ((uint4*)Wc)[idx] = o;
}

// ---------------------------------------------------------------------------
// Fused GEMM + gate epilogue — chunk-pipelined A staging.
// Block: (b,q) x 64-row tile x full 128-h slab, 8 waves (wave w owns columns
// {gg*128 + w*16 + c}, gg 0..3: softmax-coupled, register-local).
// A (64x512 bf16) lives in a single 64 KB LDS buffer, 16 kc slots, each slot
// written exactly once. Staged in 8 chunks of 64-k: at iter c, issue global
// loads for chunk c+1, MFMA chunk c (32/wave), pack+ds_write c+1, barrier.
// HBM A-stream thus overlaps MFMA + B L2 stream (phase overlap — the R4 fix).
// B streamed global->VGPR (W_comb L2-resident), rolling 1-kc prefetch.
// Epilogue reads CNN (kc 0..3) / exper (kc 12..15) back out of Abuf.
// 2 blocks/CU (128 KB LDS); launch_bounds(512,4) pins combined regs <= 128.
// ---------------------------------------------------------------------------
__global__ __launch_bounds__(512, 4) void fused_gate(
    const float* __restrict__ CNN, const float* __restrict__ gaz,
    const float* __restrict__ gazb, const float* __restrict__ gm,
    const float* __restrict__ exper, const u16* __restrict__ Wc,
    const float* __restrict__ bcat, const float* __restrict__ bexp,
    float* __restrict__ out) {
  __shared__ u16 Abuf[16 * 64 * 32];  // 64 KB

  const int tid = threadIdx.x;
  const int lane = tid & 63;
  const int wave = tid >> 6;  // 0..7
  const int bx = blockIdx.x;  // 1024: grp*8 + tile
  const int tile = bx & 7;
  const int grp = bx >> 3;
  const int b = grp >> 2;
  const int q = grp & 3;
  const int s_base = tile * 64;

  // ---- A staging thread mapping: chunk = 64 rows x 64 k (2 kc slots) ----
  const int arow = tid >> 3;  // 0..63
  const int ao = tid & 7;     // 8-elem k-octet within chunk
  const int akcl = ao >> 2;   // kc parity within chunk
  const int aoo = ao & 3;
  const int asw = (arow & 3) ^ ((arow >> 2) & 3);
  // 32-bit element offsets (SGPR base + VGPR offset addressing)
  const int cnnoff = (b * 2048 + q * 512 + s_base + arow) * HH;
  const int stdoff = (b * 512 + s_base + arow) * HH;
  const float* gz = (q & 1) ? gazb : gaz;

  // ---- stage chunk 0 (CNN k 0..63) ----
  {
    const float* sp = CNN + cnnoff + ao * 8;
    float4 f0 = *(const float4*)sp;
    float4 f1 = *(const float4*)(sp + 4);
    uint4 pk;
    pk.x = pack2(f0.x, f0.y);
    pk.y = pack2(f0.z, f0.w);
    pk.z = pack2(f1.x, f1.y);
    pk.w = pack2(f1.z, f1.w);
    const int kc = akcl;               // chunk 0: kc 0/1, sel=0
    const int ph = aoo ^ asw;          // ^ (kc>>2 == 0)
    *(uint4*)&Abuf[(kc * 64 + arow) * 32 + ph * 8] = pk;
  }
  __syncthreads();

  // ---- B setup: rolling 1-kc prefetch ----
  const int l15 = lane & 15;
  const int quad = lane >> 4;
  const int sl = (l15 & 3) ^ ((l15 >> 2) & 3);
  const int physB = quad ^ sl;
  const u16* wq = Wc + q * 262144;  // q slab (uniform)
  int nofs[4];
#pragma unroll
  for (int gg = 0; gg < 4; ++gg)
    nofs[gg] = ((gg * 128 + wave * 16 + l15) * 4 + physB) * 8;

  f32x4 acc[4][4];
#pragma unroll
  for (int rt = 0; rt < 4; ++rt)
#pragma unroll
    for (int gg = 0; gg < 4; ++gg) acc[rt][gg] = (f32x4)0.f;

  bf16x8 bcur[4], bnxt[4];
#pragma unroll
  for (int gg = 0; gg < 4; ++gg) bcur[gg] = *(const bf16x8*)(wq + nofs[gg]);

#pragma unroll
  for (int c = 0; c < 8; ++c) {
    // ---- issue A loads for chunk c+1 (before the MFMAs, to overlap) ----
    float4 f0, f1;
    if (c < 7) {
      const int cc = c + 1;
      const int sel = cc >> 1;  // compile-time (loop unrolled)
      const float* base = (sel == 0) ? CNN + cnnoff
                          : (sel == 1) ? gz + stdoff
                          : (sel == 2) ? gm + stdoff
                                       : exper + stdoff;
      const float* sp = base + (cc & 1) * 64 + ao * 8;
      f0 = *(const float4*)sp;
      f1 = *(const float4*)(sp + 4);
    }
    // ---- compute the 2 kc of chunk c ----
#pragma unroll
    for (int k2 = 0; k2 < 2; ++k2) {
      const int kc = c * 2 + k2;
      if (kc < 15) {
#pragma unroll
        for (int gg = 0; gg < 4; ++gg)
          bnxt[gg] = *(const bf16x8*)(wq + (kc + 1) * 16384 + nofs[gg]);
      }
      const int pa = (quad ^ sl ^ (kc >> 2)) * 8;
      bf16x8 af[4];
#pragma unroll
      for (int rt = 0; rt < 4; ++rt)
        af[rt] = *(const bf16x8*)&Abuf[(kc * 64 + rt * 16 + l15) * 32 + pa];
#pragma unroll
      for (int rt = 0; rt < 4; ++rt)
#pragma unroll
        for (int gg = 0; gg < 4; ++gg)
          acc[rt][gg] = __builtin_amdgcn_mfma_f32_16x16x32_bf16(
              af[rt], bcur[gg], acc[rt][gg], 0, 0, 0);
#pragma unroll
      for (int gg = 0; gg < 4; ++gg) bcur[gg] = bnxt[gg];
    }
    // ---- pack + LDS-write chunk c+1, then sync ----
    if (c < 7) {
      uint4 pk;
      pk.x = pack2(f0.x, f0.y);
      pk.y = pack2(f0.z, f0.w);
      pk.z = pack2(f1.x, f1.y);
      pk.w = pack2(f1.z, f1.w);
      const int kc = (c + 1) * 2 + akcl;
      const int ph = aoo ^ asw ^ ((c + 1) >> 1);  // kc>>2 == (c+1)>>1
      *(uint4*)&Abuf[(kc * 64 + arow) * 32 + ph * 8] = pk;
      __syncthreads();
    }
  }

  // ---- epilogue: tanh / sigmoid / softmax-of-3 / weighted state sum ----
  const float* bcq = bcat + q * 512;
  const float* beq = bexp + q * 384;
  const int outbase = ((q * 32 + b) * 512 + s_base) * HH;
  const int h = wave * 16 + l15;  // 0..127
  const float bc0 = bcq[h];
  const float bc1 = bcq[128 + h];
  const float bc2 = bcq[256 + h];
  const float bc3 = bcq[384 + h];
  const float be1 = beq[h];
  const float be2 = beq[128 + h];
  const float be3 = beq[256 + h];
  const int kcc = h >> 5;         // CNN chunk (0..3)
  const int kce = 12 + (h >> 5);  // exper chunk (12..15)
  const int oh = (h >> 3) & 3;
  const int he = h & 7;
#pragma unroll
  for (int rt = 0; rt < 4; ++rt) {
#pragma unroll
    for (int r = 0; r < 4; ++r) {
      const int row = rt * 16 + quad * 4 + r;
      const int srw = (row & 3) ^ ((row >> 2) & 3);
      const float cnn = bf2f(Abuf[(kcc * 64 + row) * 32 + (oh ^ srw) * 8 + he]);
      const float ex =
          bf2f(Abuf[(kce * 64 + row) * 32 + (oh ^ srw ^ 3) * 8 + he]);
      const float c0 = acc[rt][0][r] + bc0;
      const float p1 = acc[rt][1][r] + bc1 + be1;
      const float p2 = acc[rt][2][r] + bc2 + be2;
      const float p3 = acc[rt][3][r] + bc3 + be3;
      const float e2c = __expf(2.f * c0);
      const float ns = 1.f - 2.f * __builtin_amdgcn_rcpf(e2c + 1.f);  // tanh
      const float g1 = __builtin_amdgcn_rcpf(1.f + __expf(-p1));
      const float g2 = __builtin_amdgcn_rcpf(1.f + __expf(-p2));
      const float g3 = __builtin_amdgcn_rcpf(1.f + __expf(-p3));
      const float e1 = __expf(g1);
      const float e2 = __expf(g2);
      const float e3 = __expf(g3);
      const float inv = __builtin_amdgcn_rcpf(e1 + e2 + e3);
      out[outbase + row * HH + h] = (e1 * ns + e2 * cnn + e3 * ex) * inv;
    }
  }
}

extern "C" void kernel_launch(void* const* d_in, const int* in_sizes, int n_in,
                              void* d_out, int out_size, void* d_ws, size_t ws_size,
                              hipStream_t stream) {
  const float* CNN = (const float*)d_in[0];
  const float* gaz = (const float*)d_in[1];
  const float* gazb = (const float*)d_in[2];
  const float* gm = (const float*)d_in[3];
  const float* exper = (const float*)d_in[4];
  const float* Wcat = (const float*)d_in[5];
  const float* bcat = (const float*)d_in[6];
  const float* Wexp = (const float*)d_in[7];
  const float* bexp = (const float*)d_in[8];
  u16* Wc = (u16*)d_ws;  // 2 MB fused bf16 weights

  prep_w<<<512, 256, 0, stream>>>(Wcat, Wexp, Wc);
  fused_gate<<<1024, 512, 0, stream>>>(CNN, gaz, gazb, gm, exper, Wc, bcat,
                                       bexp, (float*)d_out);
}

// Round 6
// 158.375 us; speedup vs baseline: 1.1272x; 1.1272x over previous
//
#include <hip/hip_runtime.h>

typedef unsigned short u16;
typedef unsigned int u32;
typedef short bf16x8 __attribute__((ext_vector_type(8)));
typedef float f32x4 __attribute__((ext_vector_type(4)));

#define HH 128

__device__ __forceinline__ u16 f2bf(float f) {
  u32 u = __float_as_uint(f);
  u += 0x7fffu + ((u >> 16) & 1u);  // round-to-nearest-even
  return (u16)(u >> 16);
}
__device__ __forceinline__ u32 pack2(float a, float b) {
  return (u32)f2bf(a) | ((u32)f2bf(b) << 16);
}
__device__ __forceinline__ float bf2f(u16 h) {
  return __uint_as_float(((u32)h) << 16);
}

// ---------------------------------------------------------------------------
// Pre-pass: fused W_comb (bf16), chunk-transposed + bank-swizzled, into d_ws.
// Chunk index (((q*16+kc)*512+n)*4+p) holds W[k = kc*32 + lq*8 + j][col n],
// lq = p ^ (n&3) ^ ((n>>2)&3).
// Fused: k<384 -> W_cat[k][q*512+n]; k>=384 -> (n<128 ? 0 : W_exp[k-384][q*384+n-128])
// ---------------------------------------------------------------------------
__global__ __launch_bounds__(256) void prep_w(const float* __restrict__ Wcat,
                                              const float* __restrict__ Wexp,
                                              u16* __restrict__ Wc) {
  const int bx = blockIdx.x;      // 512 blocks: ((q*16+kc)*8 + nt)
  const int nt = bx & 7;
  const int kc = (bx >> 3) & 15;
  const int q = bx >> 7;
  __shared__ u16 T[32 * 72];      // [k-in-chunk][64 cols], stride 72 (pad)

  const int tid = threadIdx.x;
  const int r = tid >> 3;
  const int c8 = (tid & 7) * 8;
  float v[8];
  if (kc < 12) {
    const float* src =
        Wcat + (size_t)(kc * 32 + r) * 2048 + q * 512 + nt * 64 + c8;
    float4 a = *(const float4*)src;
    float4 b = *(const float4*)(src + 4);
    v[0] = a.x; v[1] = a.y; v[2] = a.z; v[3] = a.w;
    v[4] = b.x; v[5] = b.y; v[6] = b.z; v[7] = b.w;
  } else if (nt >= 2) {
    const float* src = Wexp + (size_t)((kc - 12) * 32 + r) * 1536 + q * 384 +
                       nt * 64 + c8 - 128;
    float4 a = *(const float4*)src;
    float4 b = *(const float4*)(src + 4);
    v[0] = a.x; v[1] = a.y; v[2] = a.z; v[3] = a.w;
    v[4] = b.x; v[5] = b.y; v[6] = b.z; v[7] = b.w;
  } else {
#pragma unroll
    for (int j = 0; j < 8; ++j) v[j] = 0.f;
  }
  uint4 pk;
  pk.x = pack2(v[0], v[1]);
  pk.y = pack2(v[2], v[3]);
  pk.z = pack2(v[4], v[5]);
  pk.w = pack2(v[6], v[7]);
  *(uint4*)&T[r * 72 + c8] = pk;
  __syncthreads();

  const int p = tid & 3;
  const int nl = tid >> 2;  // 0..63 local col
  const int lq = p ^ (nl & 3) ^ ((nl >> 2) & 3);
  u16 w[8];
#pragma unroll
  for (int j = 0; j < 8; ++j) w[j] = T[(lq * 8 + j) * 72 + nl];
  uint4 o;
  o.x = (u32)w[0] | ((u32)w[1] << 16);
  o.y = (u32)w[2] | ((u32)w[3] << 16);
  o.z = (u32)w[4] | ((u32)w[5] << 16);
  o.w = (u32)w[6] | ((u32)w[7] << 16);
  const size_t idx = ((size_t)((q * 16 + kc) * 512) + nt * 64 + nl) * 4 + p;
  ((uint4*)Wc)[idx] = o;
}

// ---------------------------------------------------------------------------
// Fused GEMM + gate epilogue — two-phase staging, 2 barriers total.
// Block: (b,q) x 64-row tile x full 128-h slab, 8 waves (wave w owns columns
// {gg*128 + w*16 + c}, gg 0..3: softmax-coupled, register-local).
// A (64x512 bf16) in one 64 KB LDS buffer, 16 kc slots, each written once.
// Phase 0 (CNN+gaz, kc 0..7): staged straight-line up front (transient regs).
// Phase 1 (gm+exper, kc 8..15): staged DURING kloop(0..7) as a 1-deep
// pipeline (4 persistent VGPRs), writing slots not read until the mid-barrier.
// af reads split in halves (16->8 live VGPRs) to pay for the staging regs.
// B streamed global->VGPR (W_comb L2-resident), rolling 1-kc prefetch.
// Epilogue reads CNN (kc 0..3) / exper (kc 12..15) back out of Abuf.
// 2 blocks/CU (128 KB LDS); launch_bounds(512,4) pins combined regs <= 128.
// ---------------------------------------------------------------------------
__global__ __launch_bounds__(512, 4) void fused_gate(
    const float* __restrict__ CNN, const float* __restrict__ gaz,
    const float* __restrict__ gazb, const float* __restrict__ gm,
    const float* __restrict__ exper, const u16* __restrict__ Wc,
    const float* __restrict__ bcat, const float* __restrict__ bexp,
    float* __restrict__ out) {
  __shared__ u16 Abuf[16 * 64 * 32];  // 64 KB

  const int tid = threadIdx.x;
  const int lane = tid & 63;
  const int wave = tid >> 6;  // 0..7
  const int bx = blockIdx.x;  // 1024: grp*8 + tile
  const int tile = bx & 7;
  const int grp = bx >> 3;
  const int b = grp >> 2;
  const int q = grp & 3;
  const int s_base = tile * 64;

  // ---- A staging mapping: thread -> (row, 4-float slot within a 32-k kc) ---
  const int arow = tid >> 3;  // 0..63
  const int slot = tid & 7;   // 0..7 (octet = slot>>1, half = slot&1)
  const int asw = (arow & 3) ^ ((arow >> 2) & 3);
  const int p0 = (slot >> 1) ^ asw;
  const int half4 = (slot & 1) * 4;
  const int cnnoff = (b * 2048 + q * 512 + s_base + arow) * HH + slot * 4;
  const int stdoff = (b * 512 + s_base + arow) * HH + slot * 4;
  const float* gz = (q & 1) ? gazb : gaz;

  // ---- issue phase-1 sub-chunk 0 load early (gm, k-local 0..31) ----
  float4 fcur = *(const float4*)(gm + stdoff);

  // ---- phase 0: stage kc 0..7 (CNN k0..127, gaz k128..255) ----
  {
    float4 f[8];
#pragma unroll
    for (int j = 0; j < 4; ++j)
      f[j] = *(const float4*)(CNN + cnnoff + j * 32);
#pragma unroll
    for (int j = 4; j < 8; ++j)
      f[j] = *(const float4*)(gz + stdoff + (j - 4) * 32);
#pragma unroll
    for (int j = 0; j < 8; ++j) {
      uint2 v;
      v.x = pack2(f[j].x, f[j].y);
      v.y = pack2(f[j].z, f[j].w);
      *(uint2*)&Abuf[(j * 64 + arow) * 32 + (p0 ^ (j >> 2)) * 8 + half4] = v;
    }
  }
  __syncthreads();

  // ---- B setup: rolling 1-kc prefetch ----
  const int l15 = lane & 15;
  const int quad = lane >> 4;
  const int sl = (l15 & 3) ^ ((l15 >> 2) & 3);
  const int physB = quad ^ sl;
  const u16* wq = Wc + q * 262144;  // q slab (uniform)
  int nofs[4];
#pragma unroll
  for (int gg = 0; gg < 4; ++gg)
    nofs[gg] = ((gg * 128 + wave * 16 + l15) * 4 + physB) * 8;

  f32x4 acc[4][4];
#pragma unroll
  for (int rt = 0; rt < 4; ++rt)
#pragma unroll
    for (int gg = 0; gg < 4; ++gg) acc[rt][gg] = (f32x4)0.f;

  bf16x8 bcur[4], bnxt[4];
#pragma unroll
  for (int gg = 0; gg < 4; ++gg) bcur[gg] = *(const bf16x8*)(wq + nofs[gg]);

  // ---- kloop 0..7, with phase-1 side staging (gm kc8..11, exper kc12..15) --
#pragma unroll
  for (int kc = 0; kc < 8; ++kc) {
    float4 fnxt;
    if (kc < 7) {
      const int j = kc + 1;  // compile-time
      const float* sp = (j < 4) ? gm : exper;
      fnxt = *(const float4*)(sp + stdoff + (j & 3) * 32);
    }
#pragma unroll
    for (int gg = 0; gg < 4; ++gg)
      bnxt[gg] = *(const bf16x8*)(wq + (kc + 1) * 16384 + nofs[gg]);

    const int pa = (quad ^ sl ^ (kc >> 2)) * 8;
    {
      bf16x8 a0 = *(const bf16x8*)&Abuf[(kc * 64 + l15) * 32 + pa];
      bf16x8 a1 = *(const bf16x8*)&Abuf[(kc * 64 + 16 + l15) * 32 + pa];
#pragma unroll
      for (int gg = 0; gg < 4; ++gg)
        acc[0][gg] = __builtin_amdgcn_mfma_f32_16x16x32_bf16(a0, bcur[gg],
                                                             acc[0][gg], 0, 0, 0);
#pragma unroll
      for (int gg = 0; gg < 4; ++gg)
        acc[1][gg] = __builtin_amdgcn_mfma_f32_16x16x32_bf16(a1, bcur[gg],
                                                             acc[1][gg], 0, 0, 0);
    }
    {
      bf16x8 a2 = *(const bf16x8*)&Abuf[(kc * 64 + 32 + l15) * 32 + pa];
      bf16x8 a3 = *(const bf16x8*)&Abuf[(kc * 64 + 48 + l15) * 32 + pa];
#pragma unroll
      for (int gg = 0; gg < 4; ++gg)
        acc[2][gg] = __builtin_amdgcn_mfma_f32_16x16x32_bf16(a2, bcur[gg],
                                                             acc[2][gg], 0, 0, 0);
#pragma unroll
      for (int gg = 0; gg < 4; ++gg)
        acc[3][gg] = __builtin_amdgcn_mfma_f32_16x16x32_bf16(a3, bcur[gg],
                                                             acc[3][gg], 0, 0, 0);
    }
    // ---- store phase-1 sub-chunk kc into slot 8+kc (not read until barrier)
    {
      const int dk = 8 + kc;  // compile-time
      uint2 v;
      v.x = pack2(fcur.x, fcur.y);
      v.y = pack2(fcur.z, fcur.w);
      *(uint2*)&Abuf[(dk * 64 + arow) * 32 + (p0 ^ (dk >> 2)) * 8 + half4] = v;
      fcur = fnxt;
    }
#pragma unroll
    for (int gg = 0; gg < 4; ++gg) bcur[gg] = bnxt[gg];
  }
  __syncthreads();

  // ---- kloop 8..15 (no staging) ----
#pragma unroll
  for (int kc = 8; kc < 16; ++kc) {
    if (kc < 15) {
#pragma unroll
      for (int gg = 0; gg < 4; ++gg)
        bnxt[gg] = *(const bf16x8*)(wq + (kc + 1) * 16384 + nofs[gg]);
    }
    const int pa = (quad ^ sl ^ (kc >> 2)) * 8;
    {
      bf16x8 a0 = *(const bf16x8*)&Abuf[(kc * 64 + l15) * 32 + pa];
      bf16x8 a1 = *(const bf16x8*)&Abuf[(kc * 64 + 16 + l15) * 32 + pa];
#pragma unroll
      for (int gg = 0; gg < 4; ++gg)
        acc[0][gg] = __builtin_amdgcn_mfma_f32_16x16x32_bf16(a0, bcur[gg],
                                                             acc[0][gg], 0, 0, 0);
#pragma unroll
      for (int gg = 0; gg < 4; ++gg)
        acc[1][gg] = __builtin_amdgcn_mfma_f32_16x16x32_bf16(a1, bcur[gg],
                                                             acc[1][gg], 0, 0, 0);
    }
    {
      bf16x8 a2 = *(const bf16x8*)&Abuf[(kc * 64 + 32 + l15) * 32 + pa];
      bf16x8 a3 = *(const bf16x8*)&Abuf[(kc * 64 + 48 + l15) * 32 + pa];
#pragma unroll
      for (int gg = 0; gg < 4; ++gg)
        acc[2][gg] = __builtin_amdgcn_mfma_f32_16x16x32_bf16(a2, bcur[gg],
                                                             acc[2][gg], 0, 0, 0);
#pragma unroll
      for (int gg = 0; gg < 4; ++gg)
        acc[3][gg] = __builtin_amdgcn_mfma_f32_16x16x32_bf16(a3, bcur[gg],
                                                             acc[3][gg], 0, 0, 0);
    }
#pragma unroll
    for (int gg = 0; gg < 4; ++gg) bcur[gg] = bnxt[gg];
  }

  // ---- epilogue: tanh / sigmoid / softmax-of-3 / weighted state sum ----
  const float* bcq = bcat + q * 512;
  const float* beq = bexp + q * 384;
  const int outbase = ((q * 32 + b) * 512 + s_base) * HH;
  const int h = wave * 16 + l15;  // 0..127
  const float bc0 = bcq[h];
  const float bc1 = bcq[128 + h];
  const float bc2 = bcq[256 + h];
  const float bc3 = bcq[384 + h];
  const float be1 = beq[h];
  const float be2 = beq[128 + h];
  const float be3 = beq[256 + h];
  const int kcc = h >> 5;         // CNN chunk (0..3)
  const int kce = 12 + (h >> 5);  // exper chunk (12..15)
  const int oh = (h >> 3) & 3;
  const int he = h & 7;
#pragma unroll
  for (int rt = 0; rt < 4; ++rt) {
#pragma unroll
    for (int r = 0; r < 4; ++r) {
      const int row = rt * 16 + quad * 4 + r;
      const int srw = r ^ quad;  // (row&3)^((row>>2)&3)
      const float cnn = bf2f(Abuf[(kcc * 64 + row) * 32 + (oh ^ srw) * 8 + he]);
      const float ex =
          bf2f(Abuf[(kce * 64 + row) * 32 + (oh ^ srw ^ 3) * 8 + he]);
      const float c0 = acc[rt][0][r] + bc0;
      const float p1 = acc[rt][1][r] + bc1 + be1;
      const float p2 = acc[rt][2][r] + bc2 + be2;
      const float p3 = acc[rt][3][r] + bc3 + be3;
      const float e2c = __expf(2.f * c0);
      const float ns = 1.f - 2.f * __builtin_amdgcn_rcpf(e2c + 1.f);  // tanh
      const float g1 = __builtin_amdgcn_rcpf(1.f + __expf(-p1));
      const float g2 = __builtin_amdgcn_rcpf(1.f + __expf(-p2));
      const float g3 = __builtin_amdgcn_rcpf(1.f + __expf(-p3));
      const float e1 = __expf(g1);
      const float e2 = __expf(g2);
      const float e3 = __expf(g3);
      const float inv = __builtin_amdgcn_rcpf(e1 + e2 + e3);
      out[outbase + row * HH + h] = (e1 * ns + e2 * cnn + e3 * ex) * inv;
    }
  }
}

extern "C" void kernel_launch(void* const* d_in, const int* in_sizes, int n_in,
                              void* d_out, int out_size, void* d_ws, size_t ws_size,
                              hipStream_t stream) {
  const float* CNN = (const float*)d_in[0];
  const float* gaz = (const float*)d_in[1];
  const float* gazb = (const float*)d_in[2];
  const float* gm = (const float*)d_in[3];
  const float* exper = (const float*)d_in[4];
  const float* Wcat = (const float*)d_in[5];
  const float* bcat = (const float*)d_in[6];
  const float* Wexp = (const float*)d_in[7];
  const float* bexp = (const float*)d_in[8];
  u16* Wc = (u16*)d_ws;  // 2 MB fused bf16 weights

  prep_w<<<512, 256, 0, stream>>>(Wcat, Wexp, Wc);
  fused_gate<<<1024, 512, 0, stream>>>(CNN, gaz, gazb, gm, exper, Wc, bcat,
                                       bexp, (float*)d_out);
}